// Round 11
// baseline (155.693 us; speedup 1.0000x reference)
//
#include <hip/hip_runtime.h>
#include <stdint.h>

#define D_    512
#define H_    2
#define HD_   256
#define B_    16
#define S_    1194
#define MTOK  19104          // B_*S_
#define MPAD  19200          // 150*128
#define SPAD  1216           // 19*64 = 38*32
#define NQKV  1536
#define NKT   38             // kv tiles of 32 (attn)
#define LOG2E 1.44269504088896340736f

typedef unsigned short u16;
typedef __attribute__((ext_vector_type(8))) short bf16x8;   // 8 bf16 = 4 VGPR
typedef __attribute__((ext_vector_type(4))) float f32x4;

__device__ inline u16 f2bf(float x) {
  union { float f; unsigned u; } c; c.f = x;
  unsigned r = c.u + 0x7fffu + ((c.u >> 16) & 1u);  // RNE
  return (u16)(r >> 16);
}

// async global->LDS, 16B per lane. LDS dest is wave-uniform base (HW adds
// lane*16); global src per-lane, CONTIGUOUS: 1 instr = 1KB sequential.
__device__ inline void async_copy16(void* lds, const void* g) {
  __builtin_amdgcn_global_load_lds(
      (__attribute__((address_space(1))) void*)(g),
      (__attribute__((address_space(3))) void*)(lds),
      16, 0, 0);
}

// ---------------------------------------------------------------------------
// Kernel 1 (unchanged): X/W -> frag-major bf16.
// ---------------------------------------------------------------------------
__global__ void convert_kernel(const float* __restrict__ X,
                               const float* __restrict__ Wqkv,
                               const float* __restrict__ Wout,
                               u16* __restrict__ Xf,
                               u16* __restrict__ Wqf,
                               u16* __restrict__ Wof) {
  const int NXG = MPAD * 64;
  const int NQG = 12 * 8 * 16 * 64;
  const int NOG = 4 * 8 * 16 * 64;
  const int TOT = NXG + NQG + NOG;
  int stride = gridDim.x * blockDim.x;
  for (int g = blockIdx.x * blockDim.x + threadIdx.x; g < TOT; g += stride) {
    if (g < NXG) {
      int lane = g & 63, f = (g >> 6) & 15, kt = (g >> 10) & 7, mt = g >> 13;
      int i = mt * 128 + (f & 7) * 16 + (lane & 15);
      int k = kt * 64 + (f >> 3) * 32 + (lane >> 4) * 8;
      bf16x8 o;
      if (i < MTOK) {
        f32x4 v0 = *(const f32x4*)&X[(size_t)i * 512 + k];
        f32x4 v1 = *(const f32x4*)&X[(size_t)i * 512 + k + 4];
#pragma unroll
        for (int e = 0; e < 4; ++e) { o[e] = (short)f2bf(v0[e]); o[4 + e] = (short)f2bf(v1[e]); }
      } else {
#pragma unroll
        for (int e = 0; e < 8; ++e) o[e] = 0;
      }
      *(bf16x8*)&Xf[(size_t)g * 8] = o;
    } else if (g < NXG + NQG) {
      int gg = g - NXG;
      int lane = gg & 63, f = (gg >> 6) & 15, kt = (gg >> 10) & 7, nt = gg >> 13;
      int j = nt * 128 + (f & 7) * 16 + (lane & 15);
      int k = kt * 64 + (f >> 3) * 32 + (lane >> 4) * 8;
      bf16x8 o;
#pragma unroll
      for (int e = 0; e < 8; ++e) o[e] = (short)f2bf(Wqkv[(size_t)(k + e) * NQKV + j]);
      *(bf16x8*)&Wqf[(size_t)gg * 8] = o;
    } else {
      int gg = g - NXG - NQG;
      int lane = gg & 63, f = (gg >> 6) & 15, kt = (gg >> 10) & 7, nt = gg >> 13;
      int j = nt * 128 + (f & 7) * 16 + (lane & 15);
      int k = kt * 64 + (f >> 3) * 32 + (lane >> 4) * 8;
      bf16x8 o;
#pragma unroll
      for (int e = 0; e < 8; ++e) o[e] = (short)f2bf(Wout[(size_t)(k + e) * 512 + j]);
      *(bf16x8*)&Wof[(size_t)gg * 8] = o;
    }
  }
}

// ---------------------------------------------------------------------------
// GEMM v2 (unchanged from round 10): m97 single-buffer schedule.
// ---------------------------------------------------------------------------
template<int MODE>
__global__ __launch_bounds__(256, 2) void gemm_kernel(
    const u16* __restrict__ Af, const u16* __restrict__ Bf,
    const float* __restrict__ bias, int nb,
    u16* __restrict__ Qb, u16* __restrict__ Kf, u16* __restrict__ Vf,
    float* __restrict__ Cout)
{
  __shared__ u16 ldsA[16 * 512];       // 16 KiB (single buffer)
  __shared__ u16 ldsB[16 * 512];

  const int t  = threadIdx.x;
  const int l  = t & 63;
  const int w  = t >> 6;
  const int lr = l >> 4, lc = l & 15;

  const int nwg = gridDim.x;
  const int qq = nwg >> 3, rr8 = nwg & 7;
  const int xcd = blockIdx.x & 7, off = blockIdx.x >> 3;
  const int wgid = (xcd < rr8 ? xcd * (qq + 1) : rr8 * (qq + 1) + (xcd - rr8) * qq) + off;
  const int m0 = (wgid / nb) * 128;
  const int n0 = (wgid % nb) * 128;

  const u16* pA = Af + ((size_t)(m0 >> 7) * 128 + w) * 512 + l * 8;
  const u16* pB = Bf + ((size_t)(n0 >> 7) * 128 + w) * 512 + l * 8;

  f32x4 acc[4][4] = {};

  for (int kt = 0; kt < 8; ++kt) {
    __syncthreads();                   // prev compute done: buffer reusable
    const u16* qA = pA + kt * 8192;
    const u16* qB = pB + kt * 8192;
#pragma unroll
    for (int c = 0; c < 4; ++c) {
      async_copy16(&ldsA[(c * 4 + w) * 512], qA + c * 2048);
      async_copy16(&ldsB[(c * 4 + w) * 512], qB + c * 2048);
    }
    __syncthreads();                   // stage landed (vmcnt drain)
#pragma unroll
    for (int kk = 0; kk < 2; ++kk) {
      bf16x8 af[4], bfr[4];
#pragma unroll
      for (int m = 0; m < 4; ++m)
        af[m] = *(bf16x8*)&ldsA[((kk * 8 + (w >> 1) * 4 + m) * 64 + l) * 8];
#pragma unroll
      for (int n = 0; n < 4; ++n)
        bfr[n] = *(bf16x8*)&ldsB[((kk * 8 + (w & 1) * 4 + n) * 64 + l) * 8];
      __builtin_amdgcn_s_setprio(1);
#pragma unroll
      for (int m = 0; m < 4; ++m)
#pragma unroll
        for (int n = 0; n < 4; ++n)
          acc[m][n] = __builtin_amdgcn_mfma_f32_16x16x32_bf16(af[m], bfr[n], acc[m][n], 0, 0, 0);
      __builtin_amdgcn_s_setprio(0);
    }
  }

  int jv[4]; float bj[4];
#pragma unroll
  for (int n = 0; n < 4; ++n) { jv[n] = n0 + (w & 1) * 64 + n * 16 + lc; bj[n] = bias[jv[n]]; }

#pragma unroll
  for (int m = 0; m < 4; ++m) {
#pragma unroll
    for (int r = 0; r < 4; ++r) {
      int i = m0 + (w >> 1) * 64 + m * 16 + lr * 4 + r;
      if (i >= MTOK) continue;
      if (MODE == 0) {
        int b = i / S_, s = i - b * S_;
        int stK  = s >> 5;
        int nfs  = (s >> 4) & 1;
        int lisK = s & 15;
        int lvhi = (s >> 3) & 3;
        int es   = s & 7;
#pragma unroll
        for (int n = 0; n < 4; ++n) {
          int j = jv[n];
          int which = j >> 9, h = (j >> 8) & 1, d = j & 255;
          int bh = b * H_ + h;
          u16 v = f2bf(acc[m][n][r] + bj[n]);
          if (which == 0) {
            Qb[((size_t)(bh * SPAD + s)) * HD_ + d] = v;
          } else if (which == 1) {
            Kf[(((size_t)(bh * NKT + stK)) * 16 + (d >> 5) * 2 + nfs) * 512 +
               (((d >> 3) & 3) * 16 + lisK) * 8 + (d & 7)] = v;
          } else {
            Vf[(((size_t)(bh * NKT + stK)) * 16 + (d >> 4)) * 512 +
               (lvhi * 16 + (d & 15)) * 8 + es] = v;
          }
        }
      } else {
#pragma unroll
        for (int n = 0; n < 4; ++n)
          Cout[(size_t)i * D_ + jv[n]] = acc[m][n][r] + bj[n];
      }
    }
  }
}

// ---------------------------------------------------------------------------
// Kernel 3: causal flash attention v7 = v6 + FORCED-EARLY V loads.
// Round-10 showed VGPR=100: the compiler sank the "issue-early" V loads to
// just before each PV MFMA, exposing raw L2 latency 16x per iteration.
// Fix: asm volatile global_load_dwordx4 — unsinkable, issues at placement;
// vfr stays live (VGPR ~200+). The pre-PV __syncthreads lowers to
// s_waitcnt vmcnt(0)+s_barrier, draining these loads (HW counter covers
// asm loads too), so no manual waitcnt is needed.
// ---------------------------------------------------------------------------
__global__ __launch_bounds__(256, 2) void attn_kernel(
    const u16* __restrict__ Qb, const u16* __restrict__ Kf,
    const u16* __restrict__ Vf, u16* __restrict__ Obf)
{
  __shared__ u16 ldsK[2][16 * 512];     // 2 x 16 KiB, frag = kb*2+nf
  __shared__ u16 ldsP[4][16 * 36];      // per-wave P [16 q][32 kv], pad 36

  const int id   = blockIdx.x;          // 0..607
  const int xcd  = id & 7;
  const int slot = id >> 3;             // 0..75
  const int bh   = xcd + 8 * (slot / 19);
  const int qt   = 18 - (slot % 19);    // long blocks first
  const int q0   = qt * 64;
  const int nkv  = 2 * qt + 2;          // kv tiles of 32
  const int t  = threadIdx.x, l = t & 63, w = t >> 6;
  const int lr = l >> 4, lc = l & 15;
  const int wq0 = q0 + w * 16;          // wave's first q row
  const int qrow_l = wq0 + lc;          // THIS lane's q row (swapped space)

  // Q fragments (B-operand rows=q over d): 8 d-blocks of 32
  bf16x8 qf[8];
  const u16* qbase = Qb + (size_t)(bh * SPAD + qrow_l) * HD_ + lr * 8;
#pragma unroll
  for (int kb = 0; kb < 8; ++kb)
    qf[kb] = *(const bf16x8*)(qbase + kb * 32);

  f32x4 oacc[16] = {};                  // [d-block]; col=q=lc, reg=d-sub
  float mrow = -1e30f, lsum = 0.f;      // per-lane scalars (q = lc)

  // prologue: stage K tile 0 into buf 0
  {
    const u16* kb_ = Kf + (((size_t)(bh * NKT)) * 16 + w) * 512 + l * 8;
#pragma unroll
    for (int c = 0; c < 4; ++c)
      async_copy16(&ldsK[0][(c * 4 + w) * 512], kb_ + c * 2048);
  }
  __syncthreads();

  for (int kt = 0; kt < nkv; ++kt) {
    const int cur = kt & 1;

    // (1) V-frag loads for CURRENT tile — FORCED early issue (asm volatile;
    // unsinkable). Drained by the pre-PV barrier's vmcnt(0).
    bf16x8 vfr[16];
    {
      const u16* vb_ = Vf + (((size_t)(bh * NKT + kt)) * 16) * 512 + l * 8;
#pragma unroll
      for (int nf = 0; nf < 16; ++nf)
        asm volatile("global_load_dwordx4 %0, %1, off"
                     : "=v"(vfr[nf]) : "v"(vb_ + nf * 512) : "memory");
    }

    // (2) next K tile's stages (in flight across QK + softmax)
    if (kt + 1 < nkv) {
      const u16* kb_ = Kf + (((size_t)(bh * NKT + kt + 1)) * 16 + w) * 512 + l * 8;
#pragma unroll
      for (int c = 0; c < 4; ++c)
        async_copy16(&ldsK[cur ^ 1][(c * 4 + w) * 512], kb_ + c * 2048);
    }

    // (3) S^T = K @ Q^T : A=kf (rows=kv), B=qf (rows=q) -> col=q, row=kv
    f32x4 sacc[2] = {};
    __builtin_amdgcn_s_setprio(1);
#pragma unroll
    for (int kb = 0; kb < 8; ++kb) {
#pragma unroll
      for (int nf = 0; nf < 2; ++nf) {
        bf16x8 kf = *(bf16x8*)&ldsK[cur][((kb * 2 + nf) * 64 + l) * 8];
        sacc[nf] = __builtin_amdgcn_mfma_f32_16x16x32_bf16(kf, qf[kb], sacc[nf], 0, 0, 0);
      }
    }
    __builtin_amdgcn_s_setprio(0);

    // (4) mask + scale; per-lane row-max (lane = one q-row)
    const int kv0 = kt * 32;
    float sv[2][4];
    float pm = -1e30f;
    if (kv0 + 31 <= wq0) {              // interior
#pragma unroll
      for (int nf = 0; nf < 2; ++nf)
#pragma unroll
        for (int r = 0; r < 4; ++r) {
          float v = sacc[nf][r] * 0.0625f;
          sv[nf][r] = v;
          pm = fmaxf(pm, v);
        }
    } else {
#pragma unroll
      for (int nf = 0; nf < 2; ++nf)
#pragma unroll
        for (int r = 0; r < 4; ++r) {
          int kv = kv0 + nf * 16 + lr * 4 + r;
          float v = ((kv <= qrow_l) && (kv < S_)) ? sacc[nf][r] * 0.0625f : -1e30f;
          sv[nf][r] = v;
          pm = fmaxf(pm, v);
        }
    }
    pm = fmaxf(pm, __shfl_xor(pm, 16));
    pm = fmaxf(pm, __shfl_xor(pm, 32));

    // defer-max (T13)
    bool skip = (pm <= mrow + 8.0f);
    if (!__all(skip)) {
      float mn = fmaxf(mrow, pm);
      float sc = exp2f((mrow - mn) * LOG2E);
      mrow = mn;
      lsum *= sc;
#pragma unroll
      for (int nf = 0; nf < 16; ++nf)
#pragma unroll
        for (int r = 0; r < 4; ++r) oacc[nf][r] *= sc;
    }

    // exp + P-write (packed b64)
#pragma unroll
    for (int nf = 0; nf < 2; ++nf) {
      float p0 = exp2f((sv[nf][0] - mrow) * LOG2E);
      float p1 = exp2f((sv[nf][1] - mrow) * LOG2E);
      float p2 = exp2f((sv[nf][2] - mrow) * LOG2E);
      float p3 = exp2f((sv[nf][3] - mrow) * LOG2E);
      lsum += (p0 + p1) + (p2 + p3);
      uint64_t pk = (uint64_t)f2bf(p0) | ((uint64_t)f2bf(p1) << 16) |
                    ((uint64_t)f2bf(p2) << 32) | ((uint64_t)f2bf(p3) << 48);
      *(uint64_t*)&ldsP[w][lc * 36 + nf * 16 + lr * 4] = pk;
    }

    __syncthreads();  // vmcnt(0)+s_barrier: V(kt) + K(kt+1) landed; buf swap ok

    // (5) O^T += V^T @ P^T : A=vfr (rows=d), B=pf (rows=q) -> col=q, row=d
    bf16x8 pf = *(bf16x8*)&ldsP[w][lc * 36 + lr * 8];
    __builtin_amdgcn_s_setprio(1);
#pragma unroll
    for (int nf = 0; nf < 16; ++nf)
      oacc[nf] = __builtin_amdgcn_mfma_f32_16x16x32_bf16(vfr[nf], pf, oacc[nf], 0, 0, 0);
    __builtin_amdgcn_s_setprio(0);
  }

  // finalize
  float s = lsum;
  s += __shfl_xor(s, 16);
  s += __shfl_xor(s, 32);
  float inv = 1.0f / s;

  const int b = bh >> 1, h = bh & 1;
  if (qrow_l < S_) {
    int i = b * S_ + qrow_l;
    int it = i >> 7, mf = (i >> 4) & 7, li = i & 15;
#pragma unroll
    for (int nf = 0; nf < 16; ++nf) {
#pragma unroll
      for (int r = 0; r < 4; ++r) {
        int j = h * HD_ + nf * 16 + lr * 4 + r;
        size_t addr = (((size_t)(it * 8 + (j >> 6))) * 16 + ((j >> 5) & 1) * 8 + mf) * 512 +
                      (((j >> 3) & 3) * 16 + li) * 8 + (j & 7);
        Obf[addr] = f2bf(oacc[nf][r] * inv);
      }
    }
  }
}

// ---------------------------------------------------------------------------
extern "C" void kernel_launch(void* const* d_in, const int* in_sizes, int n_in,
                              void* d_out, int out_size, void* d_ws, size_t ws_size,
                              hipStream_t stream) {
  const float* X    = (const float*)d_in[0];
  const float* Wqkv = (const float*)d_in[1];
  const float* bqkv = (const float*)d_in[2];
  const float* Wout = (const float*)d_in[3];
  const float* bout = (const float*)d_in[4];
  float* out = (float*)d_out;

  char* ws = (char*)d_ws;
  u16* Xf  = (u16*)ws;  ws += (size_t)MPAD * D_ * 2;
  u16* Wqf = (u16*)ws;  ws += (size_t)NQKV * D_ * 2;
  u16* Wof = (u16*)ws;  ws += (size_t)D_ * D_ * 2;
  u16* Qb  = (u16*)ws;  ws += (size_t)B_ * H_ * SPAD * HD_ * 2;
  u16* Kf  = (u16*)ws;  ws += (size_t)B_ * H_ * SPAD * HD_ * 2;
  u16* Vf  = (u16*)ws;  ws += (size_t)B_ * H_ * SPAD * HD_ * 2;
  u16* Obf = (u16*)ws;  ws += (size_t)MPAD * D_ * 2;
  // total ~101 MB

  convert_kernel<<<2048, 256, 0, stream>>>(X, Wqkv, Wout, Xf, Wqf, Wof);
  gemm_kernel<0><<<1800, 256, 0, stream>>>(Xf, Wqf, bqkv, 12, Qb, Kf, Vf, nullptr);
  attn_kernel<<<608, 256, 0, stream>>>(Qb, Kf, Vf, Obf);
  gemm_kernel<1><<<600, 256, 0, stream>>>(Obf, Wof, bout, 4, nullptr, nullptr, nullptr, out);
}